// Round 7
// baseline (155.530 us; speedup 1.0000x reference)
//
#include <hip/hip_runtime.h>

// ConvTranspose4d: temporal valid conv (KT=3) of ConvTranspose3d(stride 2, pad 1, k=3).
// Gather form: out[co,f,od,oh,ow] = sum_{i,ci,kd,kh,kw} x[ci,f+i,id,ih,iw] * W[ci,co,i,kd,kh,kw]
//   id=(od+1-kd)/2 valid iff parity matches; all parity-valid taps in range (24->47, 48->95).
// R7 = R4 (best, 73.7us) + ci-loop unroll 2 for load->FMA latency ILP.
//   Post-mortem trail: VALUBusy derived counter is ~2x inflated (gfx94x 4-cyc formula on
//   SIMD-32 hw); R4's true VALU-issue ~26% == 21us FMA floor / 79us -> kernel is
//   latency-stalled on the per-ci x-load chains, not instruction-bound.
//   R6 (weight pre-pack) reverted: s_loads were not the stall (85us > R4's 79).
//   R5 reverted: NOW=4 everywhere + 2x blocks blew up write RMW (219MB).
//   __launch_bounds__(192,5): cap VGPR at ~102 so unroll-2 can't drop below 5 waves/SIMD.

typedef float f4u __attribute__((ext_vector_type(4), aligned(4)));  // unaligned-ok out vec
typedef float f4a __attribute__((ext_vector_type(4)));              // 16B-aligned
typedef float f2a __attribute__((ext_vector_type(2)));              // 8B-aligned

namespace {
constexpr int T_ = 8, D_ = 24, H_ = 48, W_ = 48;
constexpr int TO = 6, DO_ = 47, HO = 95, WO = 95;
constexpr int XCS = T_ * D_ * H_ * W_;
constexpr int XFS = D_ * H_ * W_;
constexpr int XDS = H_ * W_;
constexpr long OCS = (long)TO * DO_ * HO * WO;
constexpr int OFS = DO_ * HO * WO;
constexpr int ODS = HO * WO;

// Segments: S0 = od odd & oh odd (12 taps, 4 ow/thr), S1 = od odd & oh even,
// S2 = od even & oh odd, S3 = od even & oh even. Grid = 828+414+432+432 = 2106.
constexpr int S0_END = 828, S1_END = 1242, S2_END = 1674, NWG = 2106;

template<int ND, int NH, int NOW>
__device__ __forceinline__ void conv_body(
    const float* __restrict__ x, const float* __restrict__ w,
    float* __restrict__ out, int f, int od, int oh, int t)
{
  const int iwb = (NOW == 8 ? 4 : 2) * t;
  const int TMAX = (NOW == 8) ? 11 : 23;
  const int xext = (t < TMAX) ? (NOW / 2) : 0;  // clamp: extra elem feeds only discarded ow=95

  float acc[8][NOW];
  #pragma unroll
  for (int co = 0; co < 8; ++co)
    #pragma unroll
    for (int m = 0; m < NOW; ++m) acc[co][m] = 0.f;

  #pragma unroll 2   // R7: two ci iterations in flight -> loads of ci+1 hide under FMAs of ci
  for (int ci = 0; ci < 8; ++ci) {
    // SGPR base; all weight offsets below are compile-time immediates from here.
    const float* pw = w + __builtin_amdgcn_readfirstlane(ci * 648);
    const float* pxc = x + ci * XCS + iwb;
    #pragma unroll
    for (int i = 0; i < 3; ++i) {
      #pragma unroll
      for (int a = 0; a < ND; ++a) {
        const int KD = (ND == 1) ? 1 : (a == 0 ? 0 : 2);
        const int id = (ND == 1) ? (od >> 1) : (a == 0 ? ((od + 1) >> 1) : ((od - 1) >> 1));
        #pragma unroll
        for (int b = 0; b < NH; ++b) {
          const int KH = (NH == 1) ? 1 : (b == 0 ? 0 : 2);
          const int ih = (NH == 1) ? (oh >> 1) : (b == 0 ? ((oh + 1) >> 1) : ((oh - 1) >> 1));
          const int WOFF = i * 27 + KD * 9 + KH * 3;   // compile-time
          const float* px = pxc + (f + i) * XFS + id * XDS + ih * W_;
          if (NOW == 8) {
            const f4a xa = *(const f4a*)px;            // iw = 4t..4t+3 (16B aligned)
            const float xb = px[xext];                 // iw = 4t+4
            #pragma unroll
            for (int co = 0; co < 8; ++co) {
              const float w0 = pw[co * 81 + WOFF + 0];
              const float w1 = pw[co * 81 + WOFF + 1];
              const float w2 = pw[co * 81 + WOFF + 2];
              acc[co][0] = fmaf(xa.x, w1, acc[co][0]);
              acc[co][2] = fmaf(xa.y, w1, acc[co][2]);
              acc[co][4] = fmaf(xa.z, w1, acc[co][4]);
              acc[co][6] = fmaf(xa.w, w1, acc[co][6]);
              acc[co][1] = fmaf(xa.y, w0, fmaf(xa.x, w2, acc[co][1]));
              acc[co][3] = fmaf(xa.z, w0, fmaf(xa.y, w2, acc[co][3]));
              acc[co][5] = fmaf(xa.w, w0, fmaf(xa.z, w2, acc[co][5]));
              acc[co][7] = fmaf(xb,   w0, fmaf(xa.w, w2, acc[co][7]));
            }
          } else {
            const f2a xa = *(const f2a*)px;            // iw = 2t, 2t+1 (8B aligned)
            const float x0 = xa.x, x1 = xa.y;
            const float xb = px[xext];                 // iw = 2t+2
            #pragma unroll
            for (int co = 0; co < 8; ++co) {
              const float w0 = pw[co * 81 + WOFF + 0];
              const float w1 = pw[co * 81 + WOFF + 1];
              const float w2 = pw[co * 81 + WOFF + 2];
              acc[co][0] = fmaf(x0, w1, acc[co][0]);
              acc[co][2] = fmaf(x1, w1, acc[co][2]);
              acc[co][1] = fmaf(x1, w0, fmaf(x0, w2, acc[co][1]));
              acc[co][3] = fmaf(xb, w0, fmaf(x1, w2, acc[co][3]));
            }
          }
        }
      }
    }
  }

  const long ob = (long)f * OFS + (long)od * ODS + (long)oh * HO + NOW * t;
  #pragma unroll
  for (int co = 0; co < 8; ++co) {
    float* po = out + co * OCS + ob;
    if (NOW == 8) {
      f4u lo; lo.x = acc[co][0]; lo.y = acc[co][1]; lo.z = acc[co][2]; lo.w = acc[co][3];
      *(f4u*)po = lo;
      if (t < 11) {
        f4u hi; hi.x = acc[co][4]; hi.y = acc[co][5]; hi.z = acc[co][6]; hi.w = acc[co][7];
        *(f4u*)(po + 4) = hi;
      } else {                         // ow = 88..94 (ow=95 doesn't exist)
        po[4] = acc[co][4]; po[5] = acc[co][5]; po[6] = acc[co][6];
      }
    } else {
      if (t < 23) {
        f4u v; v.x = acc[co][0]; v.y = acc[co][1]; v.z = acc[co][2]; v.w = acc[co][3];
        *(f4u*)po = v;
      } else {                         // ow = 92..94 (ow=95 doesn't exist)
        po[0] = acc[co][0]; po[1] = acc[co][1]; po[2] = acc[co][2];
      }
    }
  }
}

__global__ __launch_bounds__(192, 5) void convt4d_kernel(
    const float* __restrict__ x, const float* __restrict__ w,
    float* __restrict__ out)
{
  const int tid = threadIdx.x;
  const int bid = blockIdx.x;
  if (bid < S0_END) {                          // od odd, oh odd: 4 ow/thread
    const int ohb = bid % 6; const int rest = bid / 6;
    const int dd = rest % 23; const int f = rest / 23;
    const int od = 2 * dd + 1;
    const int t = tid % 24, yy = tid / 24;     // 24 ow-groups x 8 rows
    const int row = ohb * 8 + yy; if (row >= 47) return;
    const int oh = 2 * row + 1;
    conv_body<2, 2, 4>(x, w, out, f, od, oh, t);
  } else if (bid < S1_END) {                   // od odd, oh even
    const int b2 = bid - S0_END;
    const int ohb = b2 % 3; const int rest = b2 / 3;
    const int dd = rest % 23; const int f = rest / 23;
    const int od = 2 * dd + 1;
    const int t = tid % 12, yy = tid / 12;
    const int oh = 2 * (ohb * 16 + yy);
    conv_body<2, 1, 8>(x, w, out, f, od, oh, t);
  } else if (bid < S2_END) {                   // od even, oh odd
    const int b2 = bid - S1_END;
    const int ohb = b2 % 3; const int rest = b2 / 3;
    const int dd = rest % 24; const int f = rest / 24;
    const int od = 2 * dd;
    const int t = tid % 12, yy = tid / 12;
    const int row = ohb * 16 + yy; if (row >= 47) return;
    const int oh = 2 * row + 1;
    conv_body<1, 2, 8>(x, w, out, f, od, oh, t);
  } else {                                     // od even, oh even
    const int b2 = bid - S2_END;
    const int ohb = b2 % 3; const int rest = b2 / 3;
    const int dd = rest % 24; const int f = rest / 24;
    const int od = 2 * dd;
    const int t = tid % 12, yy = tid / 12;
    const int oh = 2 * (ohb * 16 + yy);
    conv_body<1, 1, 8>(x, w, out, f, od, oh, t);
  }
}
}  // namespace

extern "C" void kernel_launch(void* const* d_in, const int* in_sizes, int n_in,
                              void* d_out, int out_size, void* d_ws, size_t ws_size,
                              hipStream_t stream) {
  const float* x = (const float*)d_in[0];
  const float* w = (const float*)d_in[1];
  float* out = (float*)d_out;
  hipLaunchKernelGGL(convt4d_kernel, dim3(NWG), dim3(192), 0, stream, x, w, out);
}

// Round 8
// 73.144 us; speedup vs baseline: 2.1264x; 2.1264x over previous
//
#include <hip/hip_runtime.h>

// ConvTranspose4d: temporal valid conv (KT=3) of ConvTranspose3d(stride 2, pad 1, k=3).
// Gather form: out[co,f,od,oh,ow] = sum_{i,ci,kd,kh,kw} x[ci,f+i,id,ih,iw] * W[ci,co,i,kd,kh,kw]
//   id=(od+1-kd)/2 valid iff parity matches; all parity-valid taps in range (24->47, 48->95).
// R8 = R4 (best, 73.7us) + co-split 8->4 per thread (co-half = grid bit):
//   acc 64->32/16 VGPR -> target VGPR<=64 -> 8 waves/SIMD (2x residency vs R4's 4),
//   4212 blocks -> finer tail. Unlike R5, the split is along co (planes 10MB apart):
//   per-wave cache-line ownership unchanged -> no write-RMW blowup.
//   R7 lesson: launch_bounds min-waves forced VGPR=48 < acc tile -> scratch spill
//   (WRITE 375MB). Plain __launch_bounds__(192) here; VGPR count is the gate.

typedef float f4u __attribute__((ext_vector_type(4), aligned(4)));  // unaligned-ok out vec
typedef float f4a __attribute__((ext_vector_type(4)));              // 16B-aligned
typedef float f2a __attribute__((ext_vector_type(2)));              // 8B-aligned

namespace {
constexpr int T_ = 8, D_ = 24, H_ = 48, W_ = 48;
constexpr int TO = 6, DO_ = 47, HO = 95, WO = 95;
constexpr int XCS = T_ * D_ * H_ * W_;
constexpr int XFS = D_ * H_ * W_;
constexpr int XDS = H_ * W_;
constexpr long OCS = (long)TO * DO_ * HO * WO;
constexpr int OFS = DO_ * HO * WO;
constexpr int ODS = HO * WO;

// Work-id L segments (as R4): S0 = od odd & oh odd (12 taps, 4 ow/thr), S1 = od odd &
// oh even, S2 = od even & oh odd, S3 = od even & oh even. L-range = 2106; grid = 2*2106.
constexpr int S0_END = 828, S1_END = 1242, S2_END = 1674, NWG = 2 * 2106;

template<int ND, int NH, int NOW>
__device__ __forceinline__ void conv_body(
    const float* __restrict__ x, const float* __restrict__ w,
    float* __restrict__ out, int f, int od, int oh, int t, int cob)
{
  const int iwb = (NOW == 8 ? 4 : 2) * t;
  const int TMAX = (NOW == 8) ? 11 : 23;
  const int xext = (t < TMAX) ? (NOW / 2) : 0;  // clamp: extra elem feeds only discarded ow=95

  float acc[4][NOW];
  #pragma unroll
  for (int co = 0; co < 4; ++co)
    #pragma unroll
    for (int m = 0; m < NOW; ++m) acc[co][m] = 0.f;

  #pragma unroll 1
  for (int ci = 0; ci < 8; ++ci) {
    // SGPR base (ci*648 + co-half*81); all offsets below are compile-time immediates.
    const float* pw = w + __builtin_amdgcn_readfirstlane(ci * 648 + cob * 81);
    const float* pxc = x + ci * XCS + iwb;
    #pragma unroll
    for (int i = 0; i < 3; ++i) {
      #pragma unroll
      for (int a = 0; a < ND; ++a) {
        const int KD = (ND == 1) ? 1 : (a == 0 ? 0 : 2);
        const int id = (ND == 1) ? (od >> 1) : (a == 0 ? ((od + 1) >> 1) : ((od - 1) >> 1));
        #pragma unroll
        for (int b = 0; b < NH; ++b) {
          const int KH = (NH == 1) ? 1 : (b == 0 ? 0 : 2);
          const int ih = (NH == 1) ? (oh >> 1) : (b == 0 ? ((oh + 1) >> 1) : ((oh - 1) >> 1));
          const int WOFF = i * 27 + KD * 9 + KH * 3;   // compile-time
          const float* px = pxc + (f + i) * XFS + id * XDS + ih * W_;
          if (NOW == 8) {
            const f4a xa = *(const f4a*)px;            // iw = 4t..4t+3 (16B aligned)
            const float xb = px[xext];                 // iw = 4t+4
            #pragma unroll
            for (int co = 0; co < 4; ++co) {
              const float w0 = pw[co * 81 + WOFF + 0];
              const float w1 = pw[co * 81 + WOFF + 1];
              const float w2 = pw[co * 81 + WOFF + 2];
              acc[co][0] = fmaf(xa.x, w1, acc[co][0]);
              acc[co][2] = fmaf(xa.y, w1, acc[co][2]);
              acc[co][4] = fmaf(xa.z, w1, acc[co][4]);
              acc[co][6] = fmaf(xa.w, w1, acc[co][6]);
              acc[co][1] = fmaf(xa.y, w0, fmaf(xa.x, w2, acc[co][1]));
              acc[co][3] = fmaf(xa.z, w0, fmaf(xa.y, w2, acc[co][3]));
              acc[co][5] = fmaf(xa.w, w0, fmaf(xa.z, w2, acc[co][5]));
              acc[co][7] = fmaf(xb,   w0, fmaf(xa.w, w2, acc[co][7]));
            }
          } else {
            const f2a xa = *(const f2a*)px;            // iw = 2t, 2t+1 (8B aligned)
            const float x0 = xa.x, x1 = xa.y;
            const float xb = px[xext];                 // iw = 2t+2
            #pragma unroll
            for (int co = 0; co < 4; ++co) {
              const float w0 = pw[co * 81 + WOFF + 0];
              const float w1 = pw[co * 81 + WOFF + 1];
              const float w2 = pw[co * 81 + WOFF + 2];
              acc[co][0] = fmaf(x0, w1, acc[co][0]);
              acc[co][2] = fmaf(x1, w1, acc[co][2]);
              acc[co][1] = fmaf(x1, w0, fmaf(x0, w2, acc[co][1]));
              acc[co][3] = fmaf(xb, w0, fmaf(x1, w2, acc[co][3]));
            }
          }
        }
      }
    }
  }

  const long ob = (long)f * OFS + (long)od * ODS + (long)oh * HO + NOW * t;
  #pragma unroll
  for (int co = 0; co < 4; ++co) {
    float* po = out + (long)(cob + co) * OCS + ob;
    if (NOW == 8) {
      f4u lo; lo.x = acc[co][0]; lo.y = acc[co][1]; lo.z = acc[co][2]; lo.w = acc[co][3];
      *(f4u*)po = lo;
      if (t < 11) {
        f4u hi; hi.x = acc[co][4]; hi.y = acc[co][5]; hi.z = acc[co][6]; hi.w = acc[co][7];
        *(f4u*)(po + 4) = hi;
      } else {                         // ow = 88..94 (ow=95 doesn't exist)
        po[4] = acc[co][4]; po[5] = acc[co][5]; po[6] = acc[co][6];
      }
    } else {
      if (t < 23) {
        f4u v; v.x = acc[co][0]; v.y = acc[co][1]; v.z = acc[co][2]; v.w = acc[co][3];
        *(f4u*)po = v;
      } else {                         // ow = 92..94 (ow=95 doesn't exist)
        po[0] = acc[co][0]; po[1] = acc[co][1]; po[2] = acc[co][2];
      }
    }
  }
}

__global__ __launch_bounds__(192) void convt4d_kernel(
    const float* __restrict__ x, const float* __restrict__ w,
    float* __restrict__ out)
{
  const int tid = threadIdx.x;
  const int cob = (blockIdx.x & 1) * 4;        // co half: {0..3} or {4..7}
  const int L = blockIdx.x >> 1;               // work id, R4 decode
  if (L < S0_END) {                            // od odd, oh odd: 4 ow/thread
    const int ohb = L % 6; const int rest = L / 6;
    const int dd = rest % 23; const int f = rest / 23;
    const int od = 2 * dd + 1;
    const int t = tid % 24, yy = tid / 24;     // 24 ow-groups x 8 rows
    const int row = ohb * 8 + yy; if (row >= 47) return;
    const int oh = 2 * row + 1;
    conv_body<2, 2, 4>(x, w, out, f, od, oh, t, cob);
  } else if (L < S1_END) {                     // od odd, oh even
    const int b2 = L - S0_END;
    const int ohb = b2 % 3; const int rest = b2 / 3;
    const int dd = rest % 23; const int f = rest / 23;
    const int od = 2 * dd + 1;
    const int t = tid % 12, yy = tid / 12;
    const int oh = 2 * (ohb * 16 + yy);
    conv_body<2, 1, 8>(x, w, out, f, od, oh, t, cob);
  } else if (L < S2_END) {                     // od even, oh odd
    const int b2 = L - S1_END;
    const int ohb = b2 % 3; const int rest = b2 / 3;
    const int dd = rest % 24; const int f = rest / 24;
    const int od = 2 * dd;
    const int t = tid % 12, yy = tid / 12;
    const int row = ohb * 16 + yy; if (row >= 47) return;
    const int oh = 2 * row + 1;
    conv_body<1, 2, 8>(x, w, out, f, od, oh, t, cob);
  } else {                                     // od even, oh even
    const int b2 = L - S2_END;
    const int ohb = b2 % 3; const int rest = b2 / 3;
    const int dd = rest % 24; const int f = rest / 24;
    const int od = 2 * dd;
    const int t = tid % 12, yy = tid / 12;
    const int oh = 2 * (ohb * 16 + yy);
    conv_body<1, 1, 8>(x, w, out, f, od, oh, t, cob);
  }
}
}  // namespace

extern "C" void kernel_launch(void* const* d_in, const int* in_sizes, int n_in,
                              void* d_out, int out_size, void* d_ws, size_t ws_size,
                              hipStream_t stream) {
  const float* x = (const float*)d_in[0];
  const float* w = (const float*)d_in[1];
  float* out = (float*)d_out;
  hipLaunchKernelGGL(convt4d_kernel, dim3(NWG), dim3(192), 0, stream, x, w, out);
}